// Round 7
// baseline (9162.944 us; speedup 1.0000x reference)
//
#include <hip/hip_runtime.h>

#define B_   128
#define T_   1024
#define DIN  256
#define H_   512
#define DOUT 128
#define NWG  128    // 64 L0 WGs + 64 L1 WGs, 256 threads each
#define COLS 16     // h-columns per WG
#define SIH0 264    // wih0 LDS row stride (shorts), 16B-aligned
#define SW   520    // 512-col LDS row stride (shorts), 16B-aligned

typedef __attribute__((ext_vector_type(4)))  float f32x4;
typedef __attribute__((ext_vector_type(8)))  short bf16x8;
typedef __attribute__((ext_vector_type(4)))  short bf16x4;

// ---- ws byte layout ----
#define H0_OFF   0u                      // [2][64 g][128 b][8] bf16 = 256KB
#define H1_OFF   (256u << 10)            // [2][64 g][128 b][8] bf16 = 256KB
#define FIN_OFF  (512u << 10)            // [128][512] f32 = 256KB
#define BAR_OFF  (768u << 10)            // 4B
#define XB_OFF   ((768u << 10) + 256u)   // [1024][32 g][128 b][8] bf16 = 64MB
#define XB_BYTES ((size_t)T_ * 32 * 128 * 8 * 2)

__device__ __forceinline__ short f2bf(float f) {
  union { float f; unsigned u; } v; v.f = f;
  unsigned r = v.u + 0x7FFFu + ((v.u >> 16) & 1u);
  return (short)(r >> 16);
}
__device__ __forceinline__ float sigf(float x) { return 1.f / (1.f + __expf(-x)); }

__device__ __forceinline__ void st_bf(short* p, short v) {
  __hip_atomic_store((unsigned short*)p, (unsigned short)v,
                     __ATOMIC_RELAXED, __HIP_MEMORY_SCOPE_AGENT);
}
__device__ __forceinline__ void st_f32(float* p, float v) {
  __hip_atomic_store(p, v, __ATOMIC_RELAXED, __HIP_MEMORY_SCOPE_AGENT);
}
// coherent 16B fragment load, compiler-tracked
__device__ __forceinline__ bf16x8 ldfrag(const short* p) {
  union { bf16x8 v; unsigned long long q[2]; } u;
  u.q[0] = __hip_atomic_load((const unsigned long long*)p,
                             __ATOMIC_RELAXED, __HIP_MEMORY_SCOPE_AGENT);
  u.q[1] = __hip_atomic_load((const unsigned long long*)(p + 4),
                             __ATOMIC_RELAXED, __HIP_MEMORY_SCOPE_AGENT);
  return u.v;
}

__global__ void lstm_init_kernel(void* ws) {
  int gid = blockIdx.x * blockDim.x + threadIdx.x;   // 131072 threads
  unsigned* p = (unsigned*)ws;                       // h0+h1 = 512KB
  __hip_atomic_store(p + gid, 0u, __ATOMIC_RELAXED, __HIP_MEMORY_SCOPE_AGENT);
  if (gid == 0) {
    unsigned* bar = (unsigned*)((char*)ws + BAR_OFF);
    __hip_atomic_store(bar, 0u, __ATOMIC_RELAXED, __HIP_MEMORY_SCOPE_AGENT);
  }
}

// x fp32 [B][T][DIN] -> xb bf16 fragment-major [T][32 g][128 b][8]
__global__ void xconv_kernel(const float* __restrict__ x, short* __restrict__ xb) {
  int blk = blockIdx.x;            // t*32 + g
  int t = blk >> 5, g = blk & 31;
  int b = threadIdx.x >> 1, hf = (threadIdx.x & 1) * 4;
  f32x4 v = *(const f32x4*)(x + ((size_t)b * T_ + t) * DIN + g * 8 + hf);
  bf16x4 o;
#pragma unroll
  for (int j = 0; j < 4; ++j) o[j] = f2bf(v[j]);
  *(bf16x4*)(xb + ((size_t)(t * 32 + g) * 128 + b) * 8 + hf) = o;
}

extern __shared__ short smem[];

__global__ __launch_bounds__(256, 1) void lstm_coop_kernel(
    const float* __restrict__ x,
    const float* __restrict__ wih0, const float* __restrict__ whh0,
    const float* __restrict__ bih0, const float* __restrict__ bhh0,
    const float* __restrict__ wih1, const float* __restrict__ whh1,
    const float* __restrict__ bih1, const float* __restrict__ bhh1,
    const float* __restrict__ fcw,  const float* __restrict__ fcb,
    const short* __restrict__ xb,
    void* __restrict__ ws, float* __restrict__ out)
{
  const int tid  = threadIdx.x;
  const int wg   = blockIdx.x;
  const bool isL1 = wg >= 64;
  const int idx  = isL1 ? wg - 64 : wg;
  const int cg   = idx >> 1;             // [0,32) column group (16 cols)
  const int bh   = idx & 1;              // batch half (64 batches)
  const int c0   = cg * COLS;

  char* wsb = (char*)ws;
  short* h0buf = (short*)(wsb + H0_OFF);
  short* h1buf = (short*)(wsb + H1_OFF);
  float* h1fin = (float*)(wsb + FIN_OFF);
  unsigned* bar = (unsigned*)(wsb + BAR_OFF);

  // ---- stage weight slices -> LDS; row lr = mt*16 + jj*4 + gate ----
  //  (R3-verified layout, tiled x4 in M: col j = c0 + 4*mt + jj)
  if (!isL1) {
    short* sWih0 = smem;                 // [64][SIH0]
    short* sWhh0 = smem + 64 * SIH0;     // [64][SW]
    for (int i = tid; i < 64 * DIN; i += 256) {
      int lr = i >> 8, k = i & 255;
      int grow = (lr & 3) * H_ + c0 + 4 * (lr >> 4) + ((lr >> 2) & 3);
      sWih0[lr * SIH0 + k] = f2bf(wih0[(size_t)grow * DIN + k]);
    }
    for (int i = tid; i < 64 * H_; i += 256) {
      int lr = i >> 9, k = i & 511;
      int grow = (lr & 3) * H_ + c0 + 4 * (lr >> 4) + ((lr >> 2) & 3);
      sWhh0[lr * SW + k] = f2bf(whh0[(size_t)grow * H_ + k]);
    }
  } else {
    short* sWih1 = smem;                 // [64][SW]
    short* sWhh1 = smem + 64 * SW;       // [64][SW]
    for (int i = tid; i < 64 * H_; i += 256) {
      int lr = i >> 9, k = i & 511;
      int grow = (lr & 3) * H_ + c0 + 4 * (lr >> 4) + ((lr >> 2) & 3);
      sWih1[lr * SW + k] = f2bf(wih1[(size_t)grow * H_ + k]);
      sWhh1[lr * SW + k] = f2bf(whh1[(size_t)grow * H_ + k]);
    }
  }
  __syncthreads();

  const int lane = tid & 63;
  const int wid  = tid >> 6;             // wave = 16-batch tile
  const int ln   = lane & 15;            // batch-in-tile / A row / C col
  const int q    = lane >> 4;            // k-subblock / C row-group
  const int b    = bh * 64 + wid * 16 + ln;

  // biases: acc[mt][g] -> gate g, col j = c0 + 4*mt + q  (R3-verified decode)
  float bias[4][4];
#pragma unroll
  for (int mt = 0; mt < 4; ++mt)
#pragma unroll
    for (int g = 0; g < 4; ++g) {
      int grow = g * H_ + c0 + 4 * mt + q;
      bias[mt][g] = isL1 ? (bih1[grow] + bhh1[grow]) : (bih0[grow] + bhh0[grow]);
    }

  // x prefetch (L0 only): frag ks -> g = q + 4*ks, k = 32ks + 8q + e (R3 map)
  bf16x8 xp[8];
  auto xpref = [&](int t) {
    if (xb) {
      const short* p = xb + ((size_t)(t * 32 + q) * 128 + b) * 8;
#pragma unroll
      for (int ks = 0; ks < 8; ++ks) xp[ks] = *(const bf16x8*)(p + ks * 4096);
    } else {
      const float* xrow = x + ((size_t)b * T_ + t) * DIN + q * 8;
#pragma unroll
      for (int ks = 0; ks < 8; ++ks) {
        f32x4 xa = *(const f32x4*)(xrow + ks * 32);
        f32x4 xc = *(const f32x4*)(xrow + ks * 32 + 4);
#pragma unroll
        for (int j = 0; j < 4; ++j) { xp[ks][j] = f2bf(xa[j]); xp[ks][4 + j] = f2bf(xc[j]); }
      }
    }
  };
  if (!isL1) xpref(0);

  float cst[4] = {0.f, 0.f, 0.f, 0.f};

#pragma unroll 1
  for (int r = 0; r <= T_; ++r) {
    const short* h0rd = h0buf + (r & 1) * 65536;
    short*       h0wr = h0buf + ((r + 1) & 1) * 65536;
    const short* h1rd = h1buf + (r & 1) * 65536;
    short*       h1wr = h1buf + ((r + 1) & 1) * 65536;
    const bool active = isL1 ? (r >= 1) : (r < T_);

    if (active) {
      f32x4 acc[4];
#pragma unroll
      for (int mt = 0; mt < 4; ++mt)
#pragma unroll
        for (int g = 0; g < 4; ++g) acc[mt][g] = bias[mt][g];

      // coherent h fragments: frag ks -> g = q + 4*ks, k = 32ks + 8q + e (R3 map)
      const short* p0 = h0rd + q * 1024 + (size_t)b * 8;

      if (!isL1) {
        short* sWih0 = smem;
        short* sWhh0 = smem + 64 * SIH0;
        bf16x8 f0[16];
#pragma unroll
        for (int ks = 0; ks < 16; ++ks) f0[ks] = ldfrag(p0 + ks * 4096);
#pragma unroll
        for (int ks = 0; ks < 8; ++ks) {
#pragma unroll
          for (int mt = 0; mt < 4; ++mt) {
            bf16x8 a = *(const bf16x8*)(&sWih0[(mt * 16 + ln) * SIH0 + ks * 32 + q * 8]);
            acc[mt] = __builtin_amdgcn_mfma_f32_16x16x32_bf16(a, xp[ks], acc[mt], 0, 0, 0);
          }
        }
#pragma unroll
        for (int ks = 0; ks < 16; ++ks) {
#pragma unroll
          for (int mt = 0; mt < 4; ++mt) {
            bf16x8 a = *(const bf16x8*)(&sWhh0[(mt * 16 + ln) * SW + ks * 32 + q * 8]);
            acc[mt] = __builtin_amdgcn_mfma_f32_16x16x32_bf16(a, f0[ks], acc[mt], 0, 0, 0);
          }
        }
      } else {
        short* sWih1 = smem;
        short* sWhh1 = smem + 64 * SW;
        const short* p1 = h1rd + q * 1024 + (size_t)b * 8;
        bf16x8 f0[16], f1[16];
#pragma unroll
        for (int ks = 0; ks < 16; ++ks) f0[ks] = ldfrag(p0 + ks * 4096);
#pragma unroll
        for (int ks = 0; ks < 16; ++ks) f1[ks] = ldfrag(p1 + ks * 4096);
#pragma unroll
        for (int ks = 0; ks < 16; ++ks) {
#pragma unroll
          for (int mt = 0; mt < 4; ++mt) {
            bf16x8 a = *(const bf16x8*)(&sWih1[(mt * 16 + ln) * SW + ks * 32 + q * 8]);
            acc[mt] = __builtin_amdgcn_mfma_f32_16x16x32_bf16(a, f0[ks], acc[mt], 0, 0, 0);
          }
        }
#pragma unroll
        for (int ks = 0; ks < 16; ++ks) {
#pragma unroll
          for (int mt = 0; mt < 4; ++mt) {
            bf16x8 a = *(const bf16x8*)(&sWhh1[(mt * 16 + ln) * SW + ks * 32 + q * 8]);
            acc[mt] = __builtin_amdgcn_mfma_f32_16x16x32_bf16(a, f1[ks], acc[mt], 0, 0, 0);
          }
        }
      }

      // ---- elementwise (R3-verified decode): gate g = reg, col j = c0+4mt+q ----
      short* dst = isL1 ? h1wr : h0wr;
#pragma unroll
      for (int mt = 0; mt < 4; ++mt) {
        float ig = sigf(acc[mt][0]), fg = sigf(acc[mt][1]);
        float g2 = tanhf(acc[mt][2]), og = sigf(acc[mt][3]);
        float cn = fg * cst[mt] + ig * g2;
        cst[mt] = cn;
        float hn = og * tanhf(cn);
        int j = c0 + 4 * mt + q;
        st_bf(dst + (j >> 3) * 1024 + (size_t)b * 8 + (j & 7), f2bf(hn));
        if (isL1 && r == T_) st_f32(h1fin + (size_t)b * H_ + j, hn);
      }
    }

    // ---- lightweight device barrier ----
    asm volatile("s_waitcnt vmcnt(0)" ::: "memory");
    __syncthreads();
    if (tid == 0)
      __hip_atomic_fetch_add(bar, 1u, __ATOMIC_RELAXED, __HIP_MEMORY_SCOPE_AGENT);
    if (!isL1 && r + 1 < T_) xpref(r + 1);   // hide x fetch under the wait
    if (tid == 0) {
      const unsigned tgt = (unsigned)(r + 1) * NWG;
      while (__hip_atomic_load(bar, __ATOMIC_RELAXED, __HIP_MEMORY_SCOPE_AGENT) < tgt)
        __builtin_amdgcn_s_sleep(1);
    }
    __syncthreads();
    asm volatile("" ::: "memory");
  }

  // ---- FC epilogue: WG = batch row, thread = output column (R3 verbatim) ----
  if (wg < B_ && tid < DOUT) {
    const float* hrow = h1fin + (size_t)wg * H_;
    const float* wrow = fcw + (size_t)tid * H_;
    float a = fcb[tid];
    for (int j = 0; j < H_; j += 2) {
      union { unsigned long long q; float f[2]; } c;
      c.q = __hip_atomic_load((const unsigned long long*)(hrow + j),
                              __ATOMIC_RELAXED, __HIP_MEMORY_SCOPE_AGENT);
      a += c.f[0] * wrow[j] + c.f[1] * wrow[j + 1];
    }
    out[(size_t)wg * DOUT + tid] = a;
  }
}

extern "C" void kernel_launch(void* const* d_in, const int* in_sizes, int n_in,
                              void* d_out, int out_size, void* d_ws, size_t ws_size,
                              hipStream_t stream) {
  const float* x    = (const float*)d_in[0];
  const float* wih0 = (const float*)d_in[1];
  const float* whh0 = (const float*)d_in[2];
  const float* bih0 = (const float*)d_in[3];
  const float* bhh0 = (const float*)d_in[4];
  const float* wih1 = (const float*)d_in[5];
  const float* whh1 = (const float*)d_in[6];
  const float* bih1 = (const float*)d_in[7];
  const float* bhh1 = (const float*)d_in[8];
  const float* fcw  = (const float*)d_in[9];
  const float* fcb  = (const float*)d_in[10];
  float* out = (float*)d_out;

  char* wsb = (char*)d_ws;
  bool use_xb = ws_size >= (size_t)XB_OFF + XB_BYTES;
  short* xbw = use_xb ? (short*)(wsb + XB_OFF) : nullptr;
  const short* xb = xbw;

  const int dynLds = 2 * 64 * SW * 2;   // 133120 B (L1 WG requirement, max)
  hipFuncSetAttribute((const void*)lstm_coop_kernel,
                      hipFuncAttributeMaxDynamicSharedMemorySize, dynLds);

  hipLaunchKernelGGL(lstm_init_kernel, dim3(512), dim3(256), 0, stream, d_ws);
  if (use_xb)
    hipLaunchKernelGGL(xconv_kernel, dim3(T_ * 32), dim3(256), 0, stream, x, xbw);

  void* args[] = { (void*)&x, (void*)&wih0, (void*)&whh0, (void*)&bih0, (void*)&bhh0,
                   (void*)&wih1, (void*)&whh1, (void*)&bih1, (void*)&bhh1,
                   (void*)&fcw, (void*)&fcb, (void*)&xb, (void*)&d_ws, (void*)&out };
  hipLaunchCooperativeKernel((const void*)lstm_coop_kernel,
                             dim3(NWG), dim3(256), args, dynLds, stream);
}

// Round 10
// 4485.903 us; speedup vs baseline: 2.0426x; 2.0426x over previous
//
#include <hip/hip_runtime.h>

#define B_   128
#define T_   1024
#define DIN  256
#define H_   512
#define DOUT 128
#define NWG  256   // 128 column-groups x 2 batch-halves

typedef __attribute__((ext_vector_type(4))) float f32x4;
typedef __attribute__((ext_vector_type(8))) short bf16x8;
typedef __attribute__((ext_vector_type(4))) short bf16x4;

// ---- ws byte layout ----
#define H0_OFF   0u                      // [2][64][128][8] bf16 = 256KB
#define H1_OFF   (256u << 10)            // [2][64][128][8] bf16 = 256KB
#define FIN_OFF  (512u << 10)            // [128][512] f32 = 256KB
#define FLG_OFF  (768u << 10)            // flags[256] @ 128B stride = 32KB
#define XB_OFF   (800u << 10)            // [1024][32][128][8] bf16 = 64MB
#define XB_BYTES ((size_t)T_ * 32 * 128 * 8 * 2)

__device__ __forceinline__ short f2bf(float f) {
  union { float f; unsigned u; } v; v.f = f;
  unsigned r = v.u + 0x7FFFu + ((v.u >> 16) & 1u);
  return (short)(r >> 16);
}
__device__ __forceinline__ float sigf(float x) { return 1.f / (1.f + __expf(-x)); }

// agent-scope coherent access (bypasses non-coherent per-XCD L2)
__device__ __forceinline__ void st_bf(short* p, short v) {
  __hip_atomic_store((unsigned short*)p, (unsigned short)v,
                     __ATOMIC_RELAXED, __HIP_MEMORY_SCOPE_AGENT);
}
__device__ __forceinline__ void st_f32(float* p, float v) {
  __hip_atomic_store(p, v, __ATOMIC_RELAXED, __HIP_MEMORY_SCOPE_AGENT);
}
__device__ __forceinline__ void st_u32(unsigned* p, unsigned v) {
  __hip_atomic_store(p, v, __ATOMIC_RELAXED, __HIP_MEMORY_SCOPE_AGENT);
}
__device__ __forceinline__ unsigned ld_u32(const unsigned* p) {
  return __hip_atomic_load(p, __ATOMIC_RELAXED, __HIP_MEMORY_SCOPE_AGENT);
}
// coherent 16B load, no wait (caller drains vmcnt before use)
__device__ __forceinline__ void ld16(bf16x8& d, const short* p) {
  asm volatile("global_load_dwordx4 %0, %1, off sc0 sc1" : "=v"(d) : "v"(p));
}

__global__ void lstm_init_kernel(void* ws) {
  int gid = blockIdx.x * blockDim.x + threadIdx.x;   // 131072 threads
  unsigned* p = (unsigned*)ws;                       // h0+h1 = 512KB = 131072 dw
  __hip_atomic_store(p + gid, 0u, __ATOMIC_RELAXED, __HIP_MEMORY_SCOPE_AGENT);
  if (gid < 8192) {                                  // flags 32KB
    unsigned* f = (unsigned*)((char*)ws + FLG_OFF);
    __hip_atomic_store(f + gid, 0u, __ATOMIC_RELAXED, __HIP_MEMORY_SCOPE_AGENT);
  }
}

// x fp32 [B][T][DIN] -> xb bf16 fragment-major [T][32][128][8]
__global__ void xconv_kernel(const float* __restrict__ x, short* __restrict__ xb) {
  int blk = blockIdx.x;            // t*32 + g
  int t = blk >> 5, g = blk & 31;
  int b = threadIdx.x >> 1, hf = (threadIdx.x & 1) * 4;
  f32x4 v = *(const f32x4*)(x + ((size_t)b * T_ + t) * DIN + g * 8 + hf);
  bf16x4 o;
#pragma unroll
  for (int j = 0; j < 4; ++j) o[j] = f2bf(v[j]);
  *(bf16x4*)(xb + ((size_t)(t * 32 + g) * 128 + b) * 8 + hf) = o;
}

__global__ __launch_bounds__(256, 1) void lstm_coop_kernel(
    const float* __restrict__ x,
    const float* __restrict__ wih0, const float* __restrict__ whh0,
    const float* __restrict__ bih0, const float* __restrict__ bhh0,
    const float* __restrict__ wih1, const float* __restrict__ whh1,
    const float* __restrict__ bih1, const float* __restrict__ bhh1,
    const float* __restrict__ fcw,  const float* __restrict__ fcb,
    const short* __restrict__ xb,
    void* __restrict__ ws, float* __restrict__ out)
{
  __shared__ short sWih0[16][264];
  __shared__ short sWhh0[16][520];
  __shared__ short sWih1[16][520];
  __shared__ short sWhh1[16][520];

  const int tid  = threadIdx.x;
  const int wg   = blockIdx.x;
  const int cgid = wg >> 1;
  const int bh   = wg & 1;
  const int j0   = cgid * 4;

  char* wsb = (char*)ws;
  short* h0buf = (short*)(wsb + H0_OFF);
  short* h1buf = (short*)(wsb + H1_OFF);
  float* h1fin = (float*)(wsb + FIN_OFF);
  unsigned* flags = (unsigned*)(wsb + FLG_OFF);
  unsigned* ownf  = flags + wg * 32;

  // weight slices -> LDS (fp32 -> bf16 RNE); row lr = 4*jj + gate
  for (int idx = tid; idx < 16 * DIN; idx += 256) {
    int lr = idx >> 8, k = idx & 255;
    int grow = (lr & 3) * H_ + j0 + (lr >> 2);
    sWih0[lr][k] = f2bf(wih0[(size_t)grow * DIN + k]);
  }
  for (int idx = tid; idx < 16 * H_; idx += 256) {
    int lr = idx >> 9, k = idx & 511;
    int grow = (lr & 3) * H_ + j0 + (lr >> 2);
    sWhh0[lr][k] = f2bf(whh0[(size_t)grow * H_ + k]);
    sWih1[lr][k] = f2bf(wih1[(size_t)grow * H_ + k]);
    sWhh1[lr][k] = f2bf(whh1[(size_t)grow * H_ + k]);
  }
  __syncthreads();

  const int lane = tid & 63;
  const int wid  = tid >> 6;
  const int ln   = lane & 15;               // batch within tile / C col
  const int q    = lane >> 4;               // k-subblock / C row-group (jj)
  const int b    = bh * 64 + wid * 16 + ln; // this lane's batch row
  const int jj   = j0 + q;                  // this lane's h column
  const int hwof = (jj >> 3) * 1024 + (jj & 7);  // write offset (+ b*8)

  float bias0[4], bias1[4];
#pragma unroll
  for (int g = 0; g < 4; ++g) {
    int rr = g * H_ + j0 + q;
    bias0[g] = bih0[rr] + bhh0[rr];
    bias1[g] = bih1[rr] + bhh1[rr];
  }

  // x prefetch (one step ahead, plain cached loads)
  bf16x8 xp[8];
  auto xpref = [&](int t) {
    if (xb) {
      const short* p = xb + ((size_t)(t * 32 + q) * 128 + b) * 8;
#pragma unroll
      for (int ks = 0; ks < 8; ++ks) xp[ks] = *(const bf16x8*)(p + ks * 4096);
    } else {
      const float* xrow = x + ((size_t)b * T_ + t) * DIN + q * 8;
#pragma unroll
      for (int ks = 0; ks < 8; ++ks) {
        f32x4 xa = *(const f32x4*)(xrow + ks * 32);
        f32x4 xc = *(const f32x4*)(xrow + ks * 32 + 4);
#pragma unroll
        for (int j = 0; j < 4; ++j) { xp[ks][j] = f2bf(xa[j]); xp[ks][4 + j] = f2bf(xc[j]); }
      }
    }
  };
  xpref(0);

  float c0v = 0.f, c1v = 0.f;

  for (int r = 0; r <= T_; ++r) {
    const short* h0rd = h0buf + (r & 1) * 65536;
    short*       h0wr = h0buf + ((r + 1) & 1) * 65536;
    const short* h1rd = h1buf + (r & 1) * 65536;
    short*       h1wr = h1buf + ((r + 1) & 1) * 65536;

    // ---- coherent fragment loads: h0 (shared by L0-whh0 and L1-wih1) + h1 ----
    bf16x8 f0[16], f1[16];
    {
      const short* p0 = h0rd + q * 1024 + (size_t)b * 8;
      const short* p1 = h1rd + q * 1024 + (size_t)b * 8;
#pragma unroll
      for (int ks = 0; ks < 16; ++ks) ld16(f0[ks], p0 + ks * 4096);
#pragma unroll
      for (int ks = 0; ks < 16; ++ks) ld16(f1[ks], p1 + ks * 4096);
      asm volatile("s_waitcnt vmcnt(0)" ::: "memory");
      __builtin_amdgcn_sched_barrier(0);
    }

    if (r < T_) {  // layer 0, step r
      f32x4 accA, accB;
      accA[0] = bias0[0]; accA[1] = bias0[1]; accA[2] = bias0[2]; accA[3] = bias0[3];
      accB[0] = 0.f; accB[1] = 0.f; accB[2] = 0.f; accB[3] = 0.f;
#pragma unroll
      for (int ks = 0; ks < 8; ++ks) {
        bf16x8 af = *(const bf16x8*)(&sWih0[ln][ks * 32 + q * 8]);
        if (ks & 1) accB = __builtin_amdgcn_mfma_f32_16x16x32_bf16(af, xp[ks], accB, 0, 0, 0);
        else        accA = __builtin_amdgcn_mfma_f32_16x16x32_bf16(af, xp[ks], accA, 0, 0, 0);
      }
#pragma unroll
      for (int ks = 0; ks < 16; ++ks) {
        bf16x8 af = *(const bf16x8*)(&sWhh0[ln][ks * 32 + q * 8]);
        if (ks & 1) accB = __builtin_amdgcn_mfma_f32_16x16x32_bf16(af, f0[ks], accB, 0, 0, 0);
        else        accA = __builtin_amdgcn_mfma_f32_16x16x32_bf16(af, f0[ks], accA, 0, 0, 0);
      }
      f32x4 acc = accA + accB;
      float ig = sigf(acc[0]), fg = sigf(acc[1]), gg = tanhf(acc[2]), og = sigf(acc[3]);
      float cn = fg * c0v + ig * gg;
      c0v = cn;
      st_bf(h0wr + hwof + (size_t)b * 8, f2bf(og * tanhf(cn)));
    }

    if (r >= 1) {  // layer 1, step r-1
      f32x4 accA, accB;
      accA[0] = bias1[0]; accA[1] = bias1[1]; accA[2] = bias1[2]; accA[3] = bias1[3];
      accB[0] = 0.f; accB[1] = 0.f; accB[2] = 0.f; accB[3] = 0.f;
#pragma unroll
      for (int ks = 0; ks < 16; ++ks) {
        bf16x8 af = *(const bf16x8*)(&sWih1[ln][ks * 32 + q * 8]);
        if (ks & 1) accB = __builtin_amdgcn_mfma_f32_16x16x32_bf16(af, f0[ks], accB, 0, 0, 0);
        else        accA = __builtin_amdgcn_mfma_f32_16x16x32_bf16(af, f0[ks], accA, 0, 0, 0);
      }
#pragma unroll
      for (int ks = 0; ks < 16; ++ks) {
        bf16x8 af = *(const bf16x8*)(&sWhh1[ln][ks * 32 + q * 8]);
        if (ks & 1) accB = __builtin_amdgcn_mfma_f32_16x16x32_bf16(af, f1[ks], accB, 0, 0, 0);
        else        accA = __builtin_amdgcn_mfma_f32_16x16x32_bf16(af, f1[ks], accA, 0, 0, 0);
      }
      f32x4 acc = accA + accB;
      float ig = sigf(acc[0]), fg = sigf(acc[1]), gg = tanhf(acc[2]), og = sigf(acc[3]);
      float cn = fg * c1v + ig * gg;
      c1v = cn;
      float hn = og * tanhf(cn);
      st_bf(h1wr + hwof + (size_t)b * 8, f2bf(hn));
      if (r == T_) st_f32(h1fin + (size_t)b * H_ + jj, hn);
    }

    // ---- flag barrier: single store per WG, poll same-bh group's 128 flags ----
    asm volatile("s_waitcnt vmcnt(0)" ::: "memory");
    __syncthreads();
    if (tid == 0) st_u32(ownf, (unsigned)(r + 1));
    if (r + 1 < T_) xpref(r + 1);   // hide x fetch under the wait
    {
      const unsigned R = (unsigned)(r + 1);
      const unsigned* fl = flags + ((((tid & 127) << 1) | bh) << 5);
      while (ld_u32(fl) < R) __builtin_amdgcn_s_sleep(1);
    }
    __syncthreads();
    asm volatile("" ::: "memory");
  }

  // ---- wait the other bh group (h1fin complete chip-wide), then FC ----
  {
    const unsigned R = (unsigned)(T_ + 1);
    const unsigned* fl = flags + ((((tid & 127) << 1) | (bh ^ 1)) << 5);
    while (ld_u32(fl) < R) __builtin_amdgcn_s_sleep(1);
  }
  __syncthreads();
  asm volatile("" ::: "memory");

  // ---- FC epilogue: WG = batch row, thread = output column ----
  if (wg < B_ && tid < DOUT) {
    const float* hrow = h1fin + (size_t)wg * H_;
    const float* wrow = fcw + (size_t)tid * H_;
    float a = fcb[tid];
    for (int j = 0; j < H_; j += 2) {
      union { unsigned long long q; float f[2]; } c;
      c.q = __hip_atomic_load((const unsigned long long*)(hrow + j),
                              __ATOMIC_RELAXED, __HIP_MEMORY_SCOPE_AGENT);
      a += c.f[0] * wrow[j] + c.f[1] * wrow[j + 1];
    }
    out[(size_t)wg * DOUT + tid] = a;
  }
}

extern "C" void kernel_launch(void* const* d_in, const int* in_sizes, int n_in,
                              void* d_out, int out_size, void* d_ws, size_t ws_size,
                              hipStream_t stream) {
  const float* x    = (const float*)d_in[0];
  const float* wih0 = (const float*)d_in[1];
  const float* whh0 = (const float*)d_in[2];
  const float* bih0 = (const float*)d_in[3];
  const float* bhh0 = (const float*)d_in[4];
  const float* wih1 = (const float*)d_in[5];
  const float* whh1 = (const float*)d_in[6];
  const float* bih1 = (const float*)d_in[7];
  const float* bhh1 = (const float*)d_in[8];
  const float* fcw  = (const float*)d_in[9];
  const float* fcb  = (const float*)d_in[10];
  float* out = (float*)d_out;

  char* wsb = (char*)d_ws;
  bool use_xb = ws_size >= (size_t)XB_OFF + XB_BYTES;
  short* xbw = use_xb ? (short*)(wsb + XB_OFF) : nullptr;
  const short* xb = xbw;

  hipLaunchKernelGGL(lstm_init_kernel, dim3(512), dim3(256), 0, stream, d_ws);
  if (use_xb)
    hipLaunchKernelGGL(xconv_kernel, dim3(T_ * 32), dim3(256), 0, stream, x, xbw);

  void* args[] = { (void*)&x, (void*)&wih0, (void*)&whh0, (void*)&bih0, (void*)&bhh0,
                   (void*)&wih1, (void*)&whh1, (void*)&bih1, (void*)&bhh1,
                   (void*)&fcw, (void*)&fcb, (void*)&xb, (void*)&d_ws, (void*)&out };
  hipLaunchCooperativeKernel((const void*)lstm_coop_kernel,
                             dim3(NWG), dim3(256), args, 0, stream);
}